// Round 11
// baseline (129.394 us; speedup 1.0000x reference)
//
#include <hip/hip_runtime.h>
#include <cstdint>
#include <cstddef>

#define BSTRIDE 98304   // 1024*96 floats per batch

typedef __attribute__((ext_vector_type(8))) short short8;
typedef __attribute__((ext_vector_type(4))) float f32x4;

__device__ __forceinline__ uint16_t f2bf(float x) {
    uint32_t u = __float_as_uint(x);
    return (uint16_t)((u + 0x7FFF + ((u >> 16) & 1)) >> 16);   // RNE
}
__device__ __forceinline__ float bf2f(uint16_t b) {
    return __uint_as_float(((uint32_t)b) << 16);
}
__device__ __forceinline__ short8 mk8(uint2 lo, uint2 hi) {
    union { short8 s; uint2 u[2]; } r;
    r.u[0] = lo; r.u[1] = hi;
    return r.s;
}

// ---------------------------------------------------------------------------
// kA: proj + LN (+ Linker transpose).  384 thr.  (r4/r10 structure, verbatim)
// ---------------------------------------------------------------------------
union SmemA {
    struct {
        union {
            float M[96][97];                         // 37248 B
            struct { float zb[16][97]; float ps1[16][8];
                     float ps2[16][8]; float stats[16][2]; } ln;
        } m;
        float xs[16][96];                            // 6144 B
    } a;                                             // ~43.4 KB
    struct { float T[64][65]; } kl;
};

__global__ __launch_bounds__(384, 4) void kA(
    const float* __restrict__ x, const float* __restrict__ M,
    const float* __restrict__ L,
    const float* __restrict__ gamma, const float* __restrict__ beta,
    float* __restrict__ Z0, float* __restrict__ Z, uint16_t* __restrict__ Lt)
{
    __shared__ SmemA sm;
    const int t  = threadIdx.x;
    const int bx = blockIdx.x;

    if (bx >= 512) {
        const int bx2 = bx - 512;
        const int s0 = (bx2 & 15) * 64, t0 = (bx2 >> 4) * 64;
        if (t < 64) {
            for (int r = 0; r < 64; ++r)
                sm.kl.T[r][t] = L[(size_t)(s0 + r) * 1024 + t0 + t];
        }
        __syncthreads();
        if (t < 64) {
            uint16_t* orow = Lt + (size_t)(t0 + t) * 1024 + s0;
            #pragma unroll
            for (int c4 = 0; c4 < 16; ++c4) {
                uint32_t u01 = (uint32_t)f2bf(sm.kl.T[c4*4+0][t]) |
                               ((uint32_t)f2bf(sm.kl.T[c4*4+1][t]) << 16);
                uint32_t u23 = (uint32_t)f2bf(sm.kl.T[c4*4+2][t]) |
                               ((uint32_t)f2bf(sm.kl.T[c4*4+3][t]) << 16);
                uint2 o; o.x = u01; o.y = u23;
                *(uint2*)(orow + c4 * 4) = o;
            }
        }
        return;
    }

    const int R0 = bx * 16;               // 16 rows, all same b (16 | 1024)
    const int b  = R0 >> 10;
    const int sb = R0 & 1023;

    #pragma unroll
    for (int k = 0; k < 6; ++k) {
        int mm = t + 384 * k;
        int i = mm / 24, j0 = (mm % 24) * 4;
        float4 v = *(const float4*)(M + (size_t)i * 96 + j0);
        sm.a.m.M[i][j0]   = v.x; sm.a.m.M[i][j0+1] = v.y;
        sm.a.m.M[i][j0+2] = v.z; sm.a.m.M[i][j0+3] = v.w;
    }
    {
        int row = t / 24, j0 = (t % 24) * 4;
        float4 v = *(const float4*)(x + (size_t)(R0 + row) * 96 + j0);
        *(float4*)&sm.a.xs[row][j0] = v;
    }
    __syncthreads();

    const int e = t % 96;     // feature i
    const int q = t / 96;     // row quarter
    float acc[4] = {0.f, 0.f, 0.f, 0.f};
    for (int j0 = 0; j0 < 96; j0 += 4) {
        float m0 = sm.a.m.M[e][j0+0], m1 = sm.a.m.M[e][j0+1];
        float m2 = sm.a.m.M[e][j0+2], m3 = sm.a.m.M[e][j0+3];
        #pragma unroll
        for (int rr = 0; rr < 4; ++rr) {
            float4 xv = *(const float4*)&sm.a.xs[q * 4 + rr][j0];
            acc[rr] = fmaf(m0, xv.x, fmaf(m1, xv.y,
                      fmaf(m2, xv.z, fmaf(m3, xv.w, acc[rr]))));
        }
    }
    __syncthreads();
    #pragma unroll
    for (int rr = 0; rr < 4; ++rr) sm.a.m.ln.zb[q * 4 + rr][e] = acc[rr];
    __syncthreads();

    if (t < 128) {
        int r = t >> 3, seg = t & 7;
        float s1 = 0.f, s2 = 0.f;
        #pragma unroll
        for (int k = 0; k < 12; ++k) {
            float v = sm.a.m.ln.zb[r][seg * 12 + k];
            s1 += v; s2 += v * v;
        }
        sm.a.m.ln.ps1[r][seg] = s1; sm.a.m.ln.ps2[r][seg] = s2;
    }
    __syncthreads();
    if (t < 16) {
        float s1 = 0.f, s2 = 0.f;
        #pragma unroll
        for (int k = 0; k < 8; ++k) { s1 += sm.a.m.ln.ps1[t][k]; s2 += sm.a.m.ln.ps2[t][k]; }
        float mu  = s1 * (1.f / 96.f);
        float var = s2 * (1.f / 96.f) - mu * mu;
        sm.a.m.ln.stats[t][0] = mu;
        sm.a.m.ln.stats[t][1] = rsqrtf(var + 1e-5f);
    }
    __syncthreads();

    {
        float gm = gamma[e], bt = beta[e];
        #pragma unroll
        for (int rr = 0; rr < 4; ++rr) {
            int r = q * 4 + rr;
            float z  = acc[rr];
            float mu = sm.a.m.ln.stats[r][0], rs = sm.a.m.ln.stats[r][1];
            size_t o = (size_t)(sb + r) * 768 + (size_t)b * 96 + e;
            Z0[o] = z;
            Z[o]  = (z - mu) * rs * gm + bt;
        }
    }
}

// ---------------------------------------------------------------------------
// kB: W-gen (Chebyshev over 4 s) + apply.  2048 blocks = 8 ih x 256 sg.
//   ih-MAJOR grid: sg = bid&255 -> bid%8 = sg%8 -> all 8 ih-blocks sharing
//   one sg's 12-KB Z slice on the SAME XCD (read locality, r10-proven).
//   Vt sg-TILED [256][768][4]: block writes a private 768-B region; line
//   sharing only across same-XCD ih-blocks (r10-proven safe).
//   LDS 23.5 KB -> 5 blocks/CU (wave-capped).  Async reg-prefetch of P and
//   Z held through phase A (r9-verified math, r9's write path replaced).
// ---------------------------------------------------------------------------
struct SmemB {
    float    zs[4][8][100];    // [s'][b][j] f32, pad 100 (12800 B)
    uint16_t W[4][12][104];    // [s'][i'][j] bf16, row 208 B 16-aligned (9984 B)
    uint16_t stage[12][8][4];  // [i'][b][s'] (768 B)   -> 23552 B total
};

__global__ __launch_bounds__(384, 6) void kB(
    const float* __restrict__ P, const float* __restrict__ Z,
    const float* __restrict__ Z0, uint16_t* __restrict__ Vt)
{
    __shared__ SmemB sm;
    const int t  = threadIdx.x;
    const int sg = blockIdx.x & 255;      // [0,256)  -> XCD = sg%8
    const int ih = blockIdx.x >> 8;       // [0,8)
    const int s0 = sg * 4;
    const int i0 = ih * 12;

    const int j   = t % 96;
    const int iqb = t / 96;

    // ---- prefetch P (3 pairs, 32 B each) into regs ----
    float4 pA[3], pB[3];
    #pragma unroll
    for (int kk = 0; kk < 3; ++kk) {
        const int ig = i0 + kk * 4 + iqb;
        const float* Pp = P + ((size_t)ig * 96 + j) * 8;
        pA[kk] = *(const float4*)(Pp);
        pB[kk] = *(const float4*)(Pp + 4);
    }
    // ---- prefetch Z slice into regs (LDS-written after phase A) ----
    float4 zreg[2];
    #pragma unroll
    for (int r = 0; r < 2; ++r) {
        int c = t + 384 * r;              // f32x4 chunk id, [0,768)
        zreg[r] = *(const float4*)(Z + (size_t)s0 * 768 + (size_t)c * 4);
    }

    // ---- phase A: thread (j, iqb): W[j][ip] via Chebyshev over 4 s ----
    {
        const float sf  = (float)s0;
        const float sm1 = sf - 1.0f;
        #pragma unroll 1
        for (int kk = 0; kk < 3; ++kk) {
            const int ip = kk * 4 + iqb;            // i' in [0,12)
            const int ig = i0 + ip;
            float pv[8] = {pA[kk].x, pA[kk].y, pA[kk].z, pA[kk].w,
                           pB[kk].x, pB[kk].y, pB[kk].z, pB[kk].w};
            float base = (float)((ig * 96 + j) * 8 + 2);   // exact (<2^23)
            float c[8], cp[8], tc[8];
            #pragma unroll
            for (int g = 0; g < 8; ++g) {
                float inv = __builtin_amdgcn_rcpf(base + (float)g);
                tc[g] = 2.0f * __builtin_amdgcn_cosf(inv);
                c[g]  = __builtin_amdgcn_cosf(__builtin_amdgcn_fractf(sf  * inv));
                cp[g] = __builtin_amdgcn_cosf(__builtin_amdgcn_fractf(sm1 * inv));
            }
            #pragma unroll
            for (int sp = 0; sp < 4; ++sp) {
                float w = 0.f;
                #pragma unroll
                for (int g = 0; g < 8; ++g) w = fmaf(pv[g], c[g], w);
                sm.W[sp][ip][j] = f2bf(w);
                #pragma unroll
                for (int g = 0; g < 8; ++g) {
                    float cn = fmaf(tc[g], c[g], -cp[g]);
                    cp[g] = c[g]; c[g] = cn;
                }
            }
        }
    }

    // ---- late zs LDS-write (global latency hidden under phase A) ----
    #pragma unroll
    for (int r = 0; r < 2; ++r) {
        int c = t + 384 * r;
        int elem = c * 4;
        int sp = elem / 768;
        int rem = elem - sp * 768;
        int bb = rem / 96, j0 = rem - bb * 96;
        *(float4*)&sm.zs[sp][bb][j0] = zreg[r];
    }

    // ---- prefetch residual before the barrier ----
    const int s2   = t / 96;
    const int rem2 = t % 96;
    const int ipq  = rem2 >> 3;           // [0,12)
    const int bb2  = rem2 & 7;
    float res = Z0[(size_t)(s0 + s2) * 768 + (size_t)bb2 * 96 + i0 + ipq];
    __syncthreads();

    // ---- phase B: thread (s2, ipq, bb2): 1 i' x 96 j ----
    {
        float a0 = 0.f, a1 = 0.f, a2 = 0.f, a3 = 0.f;
        const uint16_t* w0 = &sm.W[s2][ipq][0];
        const float*    zz = &sm.zs[s2][bb2][0];
        #pragma unroll 3
        for (int j0 = 0; j0 < 96; j0 += 8) {
            short8 wa = *(const short8*)(w0 + j0);
            float4 z0v = *(const float4*)(zz + j0);
            float4 z1v = *(const float4*)(zz + j0 + 4);
            a0 = fmaf(bf2f((uint16_t)wa[0]), z0v.x, a0);
            a1 = fmaf(bf2f((uint16_t)wa[1]), z0v.y, a1);
            a2 = fmaf(bf2f((uint16_t)wa[2]), z0v.z, a2);
            a3 = fmaf(bf2f((uint16_t)wa[3]), z0v.w, a3);
            a0 = fmaf(bf2f((uint16_t)wa[4]), z1v.x, a0);
            a1 = fmaf(bf2f((uint16_t)wa[5]), z1v.y, a1);
            a2 = fmaf(bf2f((uint16_t)wa[6]), z1v.z, a2);
            a3 = fmaf(bf2f((uint16_t)wa[7]), z1v.w, a3);
        }
        float acc = (a0 + a1) + (a2 + a3);
        sm.stage[ipq][bb2][s2] = f2bf(acc + res);
    }
    __syncthreads();

    // ---- Vt write (sg-tiled): 8 B per (b,i) row into block-private region --
    if (t < 96) {
        int ip = t >> 3, bb = t & 7;
        uint2 v = *(const uint2*)&sm.stage[ip][bb][0];
        *(uint2*)(Vt + ((size_t)sg * 768 + (size_t)bb * 96 + i0 + ip) * 4) = v;
    }
}

// ---------------------------------------------------------------------------
// K3: out[b,t,i] = sum_s Lt[t][s]*Vt_tiled[s/4][b*96+i][s%4]
// Split-K x4 + i-half z-split: grid (64,8,2), 256 thr, LDS combine.
// B-operand short8 spans two adjacent sg-tiles -> built from two uint2 loads.
// ---------------------------------------------------------------------------
__global__ __launch_bounds__(256, 4) void k3_mfma(
    const uint16_t* __restrict__ Lt, const uint16_t* __restrict__ Vt,
    float* __restrict__ out)
{
    __shared__ float racc[3][64][13];
    const int lane = threadIdx.x & 63;
    const int kw   = threadIdx.x >> 6;      // 0..3
    const int m    = lane & 15;
    const int quad = lane >> 4;
    const int t0   = blockIdx.x * 16;
    const int b    = blockIdx.y;
    const int ih   = blockIdx.z;            // i-half

    const uint16_t* Lp = Lt + (size_t)(t0 + m) * 1024 + kw * 256 + quad * 8;
    // s = kw*256 + quad*8 + kc*32 + e  ->  sg = kw*64 + quad*2 + kc*8 (+1 for e>=4)
    const int sgA0    = kw * 64 + quad * 2;
    const int rowBase = b * 96 + ih * 48 + m;

    f32x4 acc[3];
    #pragma unroll
    for (int ii = 0; ii < 3; ++ii) acc[ii] = (f32x4){0.f, 0.f, 0.f, 0.f};

    short8 a = *(const short8*)Lp;
    short8 bv[3];
    #pragma unroll
    for (int ii = 0; ii < 3; ++ii) {
        size_t base = ((size_t)sgA0 * 768 + rowBase + ii * 16) * 4;
        bv[ii] = mk8(*(const uint2*)(Vt + base),
                     *(const uint2*)(Vt + base + 3072));
    }

    for (int kc = 0; kc < 7; ++kc) {
        short8 an = *(const short8*)(Lp + (kc + 1) * 32);
        short8 bn[3];
        #pragma unroll
        for (int ii = 0; ii < 3; ++ii) {
            size_t base = ((size_t)(sgA0 + (kc + 1) * 8) * 768 + rowBase + ii * 16) * 4;
            bn[ii] = mk8(*(const uint2*)(Vt + base),
                         *(const uint2*)(Vt + base + 3072));
        }
        #pragma unroll
        for (int ii = 0; ii < 3; ++ii)
            acc[ii] = __builtin_amdgcn_mfma_f32_16x16x32_bf16(a, bv[ii], acc[ii], 0, 0, 0);
        a = an;
        #pragma unroll
        for (int ii = 0; ii < 3; ++ii) bv[ii] = bn[ii];
    }
    #pragma unroll
    for (int ii = 0; ii < 3; ++ii)
        acc[ii] = __builtin_amdgcn_mfma_f32_16x16x32_bf16(a, bv[ii], acc[ii], 0, 0, 0);

    if (kw > 0) {
        #pragma unroll
        for (int ii = 0; ii < 3; ++ii)
            #pragma unroll
            for (int r = 0; r < 4; ++r)
                racc[kw - 1][lane][ii * 4 + r] = acc[ii][r];
    }
    __syncthreads();
    if (kw == 0) {
        float* po = out + (size_t)b * BSTRIDE;
        #pragma unroll
        for (int ii = 0; ii < 3; ++ii)
            #pragma unroll
            for (int r = 0; r < 4; ++r)
                po[(size_t)(t0 + quad * 4 + r) * 96 + ih * 48 + ii * 16 + m] =
                    acc[ii][r] + racc[0][lane][ii * 4 + r] +
                    racc[1][lane][ii * 4 + r] + racc[2][lane][ii * 4 + r];
    }
}

extern "C" void kernel_launch(void* const* d_in, const int* in_sizes, int n_in,
                              void* d_out, int out_size, void* d_ws, size_t ws_size,
                              hipStream_t stream)
{
    const float* x     = (const float*)d_in[0];
    const float* M     = (const float*)d_in[1];
    const float* P     = (const float*)d_in[2];
    const float* Lnk   = (const float*)d_in[3];
    const float* gamma = (const float*)d_in[4];
    const float* beta  = (const float*)d_in[5];
    float* out = (float*)d_out;

    uint8_t* ws = (uint8_t*)d_ws;
    uint16_t* Lt = (uint16_t*)ws;                 // 2,097,152 B
    uint16_t* Vt = (uint16_t*)(ws + 2097152);     // 1,572,864 B (tiled [256][768][4])
    float*    Z0 = (float*)(ws + 3670016);        // 3,145,728 B
    float*    Z  = (float*)(ws + 6815744);        // 3,145,728 B

    kA<<<768, 384, 0, stream>>>(x, M, Lnk, gamma, beta, Z0, Z, Lt);
    kB<<<2048, 384, 0, stream>>>(P, Z, Z0, Vt);
    k3_mfma<<<dim3(64, 8, 2), 256, 0, stream>>>(Lt, Vt, out);
}

// Round 12
// 106.419 us; speedup vs baseline: 1.2159x; 1.2159x over previous
//
#include <hip/hip_runtime.h>
#include <cstdint>
#include <cstddef>

#define BSTRIDE 98304   // 1024*96 floats per batch

typedef __attribute__((ext_vector_type(8))) short short8;
typedef __attribute__((ext_vector_type(4))) float f32x4;

__device__ __forceinline__ uint16_t f2bf(float x) {
    uint32_t u = __float_as_uint(x);
    return (uint16_t)((u + 0x7FFF + ((u >> 16) & 1)) >> 16);   // RNE
}
__device__ __forceinline__ float bf2f(uint16_t b) {
    return __uint_as_float(((uint32_t)b) << 16);
}

// ---------------------------------------------------------------------------
// kA: proj + LN (+ Linker transpose).  384 thr.  (r4 structure, verbatim)
//   blocks [0,512):   16 global rows (b,s) each: Z0/Z in layout [s][b][i] f32
//   blocks [512,768): Lt[t][s] = bf16(Linker[s][t])  (64x64 tiles, proven)
// ---------------------------------------------------------------------------
union SmemA {
    struct {
        union {
            float M[96][97];                         // 37248 B
            struct { float zb[16][97]; float ps1[16][8];
                     float ps2[16][8]; float stats[16][2]; } ln;
        } m;
        float xs[16][96];                            // 6144 B
    } a;                                             // ~43.4 KB
    struct { float T[64][65]; } kl;
};

__global__ __launch_bounds__(384, 4) void kA(
    const float* __restrict__ x, const float* __restrict__ M,
    const float* __restrict__ L,
    const float* __restrict__ gamma, const float* __restrict__ beta,
    float* __restrict__ Z0, float* __restrict__ Z, uint16_t* __restrict__ Lt)
{
    __shared__ SmemA sm;
    const int t  = threadIdx.x;
    const int bx = blockIdx.x;

    if (bx >= 512) {
        const int bx2 = bx - 512;
        const int s0 = (bx2 & 15) * 64, t0 = (bx2 >> 4) * 64;
        if (t < 64) {
            for (int r = 0; r < 64; ++r)
                sm.kl.T[r][t] = L[(size_t)(s0 + r) * 1024 + t0 + t];
        }
        __syncthreads();
        if (t < 64) {
            uint16_t* orow = Lt + (size_t)(t0 + t) * 1024 + s0;
            #pragma unroll
            for (int c4 = 0; c4 < 16; ++c4) {
                uint32_t u01 = (uint32_t)f2bf(sm.kl.T[c4*4+0][t]) |
                               ((uint32_t)f2bf(sm.kl.T[c4*4+1][t]) << 16);
                uint32_t u23 = (uint32_t)f2bf(sm.kl.T[c4*4+2][t]) |
                               ((uint32_t)f2bf(sm.kl.T[c4*4+3][t]) << 16);
                uint2 o; o.x = u01; o.y = u23;
                *(uint2*)(orow + c4 * 4) = o;
            }
        }
        return;
    }

    const int R0 = bx * 16;               // 16 rows, all same b (16 | 1024)
    const int b  = R0 >> 10;
    const int sb = R0 & 1023;

    // ---- stage M (96x96) into LDS, padded row 97 ----
    #pragma unroll
    for (int k = 0; k < 6; ++k) {
        int mm = t + 384 * k;
        int i = mm / 24, j0 = (mm % 24) * 4;
        float4 v = *(const float4*)(M + (size_t)i * 96 + j0);
        sm.a.m.M[i][j0]   = v.x; sm.a.m.M[i][j0+1] = v.y;
        sm.a.m.M[i][j0+2] = v.z; sm.a.m.M[i][j0+3] = v.w;
    }
    // ---- stage x rows ----
    {
        int row = t / 24, j0 = (t % 24) * 4;
        float4 v = *(const float4*)(x + (size_t)(R0 + row) * 96 + j0);
        *(float4*)&sm.a.xs[row][j0] = v;
    }
    __syncthreads();

    const int e = t % 96;     // feature i
    const int q = t / 96;     // row quarter
    float acc[4] = {0.f, 0.f, 0.f, 0.f};
    for (int j0 = 0; j0 < 96; j0 += 4) {
        float m0 = sm.a.m.M[e][j0+0], m1 = sm.a.m.M[e][j0+1];
        float m2 = sm.a.m.M[e][j0+2], m3 = sm.a.m.M[e][j0+3];
        #pragma unroll
        for (int rr = 0; rr < 4; ++rr) {
            float4 xv = *(const float4*)&sm.a.xs[q * 4 + rr][j0];
            acc[rr] = fmaf(m0, xv.x, fmaf(m1, xv.y,
                      fmaf(m2, xv.z, fmaf(m3, xv.w, acc[rr]))));
        }
    }
    __syncthreads();          // all M reads done; ln region aliases M
    #pragma unroll
    for (int rr = 0; rr < 4; ++rr) sm.a.m.ln.zb[q * 4 + rr][e] = acc[rr];
    __syncthreads();

    if (t < 128) {            // 16 rows x 8 segments of 12
        int r = t >> 3, seg = t & 7;
        float s1 = 0.f, s2 = 0.f;
        #pragma unroll
        for (int k = 0; k < 12; ++k) {
            float v = sm.a.m.ln.zb[r][seg * 12 + k];
            s1 += v; s2 += v * v;
        }
        sm.a.m.ln.ps1[r][seg] = s1; sm.a.m.ln.ps2[r][seg] = s2;
    }
    __syncthreads();
    if (t < 16) {
        float s1 = 0.f, s2 = 0.f;
        #pragma unroll
        for (int k = 0; k < 8; ++k) { s1 += sm.a.m.ln.ps1[t][k]; s2 += sm.a.m.ln.ps2[t][k]; }
        float mu  = s1 * (1.f / 96.f);
        float var = s2 * (1.f / 96.f) - mu * mu;
        sm.a.m.ln.stats[t][0] = mu;
        sm.a.m.ln.stats[t][1] = rsqrtf(var + 1e-5f);
    }
    __syncthreads();

    {   // write Z0 (raw) and Z (LN'd), layout [s][b][i], coalesced in i
        float gm = gamma[e], bt = beta[e];
        #pragma unroll
        for (int rr = 0; rr < 4; ++rr) {
            int r = q * 4 + rr;
            float z  = acc[rr];
            float mu = sm.a.m.ln.stats[r][0], rs = sm.a.m.ln.stats[r][1];
            size_t o = (size_t)(sb + r) * 768 + (size_t)b * 96 + e;
            Z0[o] = z;
            Z[o]  = (z - mu) * rs * gm + bt;
        }
    }
}

// ---------------------------------------------------------------------------
// kB: W-gen (Chebyshev over 8 s) + apply.  1024 blocks = 8 ih x 128 sg.
//   ih-MAJOR grid (sg = bid&127): all 8 ih-blocks sharing one sg's 24-KB Z
//   slice have bid%8 = sg%8 -> SAME XCD -> Z fetched once per sg (not 8x).
//   Vt is sg-TILED [sg][row][8]: each block writes a private contiguous
//   region -> full-line single-XCD ownership (no cross-XCD write
//   amplification, structurally).  Everything else identical to r4.
// ---------------------------------------------------------------------------
struct SmemB {
    float    zs[8][8][100];    // [s'][b][j] f32, pad 100 -> conflict-free (25600)
    uint16_t W[8][12][104];    // [s'][i'][j] bf16, row 208 B 16-aligned (19968)
    uint16_t stage[12][8][8];  // [i'][b][s'] (1536)
};

__global__ __launch_bounds__(384, 4) void kB(
    const float* __restrict__ P, const float* __restrict__ Z,
    const float* __restrict__ Z0, uint16_t* __restrict__ Vt)
{
    __shared__ SmemB sm;
    const int t  = threadIdx.x;
    const int sg = blockIdx.x & 127;      // [0,128)  -> XCD = sg%8 (shared by all ih)
    const int ih = blockIdx.x >> 7;       // [0,8)
    const int s0 = sg * 8;
    const int i0 = ih * 12;

    // ---- load zs: Z[(s0..s0+7)][b][j] = 24 KB contiguous ----
    #pragma unroll
    for (int k = 0; k < 4; ++k) {
        int c = t + 384 * k;              // f32x4 chunk id, [0,1536)
        int elem = c * 4;
        int sp = elem / 768, rem = elem - sp * 768;
        int bb = rem / 96,  j0 = rem - bb * 96;
        float4 v = *(const float4*)(Z + (size_t)s0 * 768 + elem);
        *(float4*)&sm.zs[sp][bb][j0] = v;
    }

    // ---- phase A: thread (j = t%96, iqb = t/96), 3 pairs ----
    {
        const int j   = t % 96;
        const int iqb = t / 96;
        const float sf  = (float)s0;
        const float sm1 = sf - 1.0f;
        #pragma unroll 1
        for (int kk = 0; kk < 3; ++kk) {
            const int ip = kk * 4 + iqb;            // i' in [0,12)
            const int ig = i0 + ip;
            const float* Pp = P + ((size_t)ig * 96 + j) * 8;
            float4 pa = *(const float4*)(Pp);
            float4 pb = *(const float4*)(Pp + 4);
            float pv[8] = {pa.x, pa.y, pa.z, pa.w, pb.x, pb.y, pb.z, pb.w};
            float base = (float)((ig * 96 + j) * 8 + 2);   // exact (<2^23)
            float c[8], cp[8], tc[8];
            #pragma unroll
            for (int g = 0; g < 8; ++g) {
                float inv = __builtin_amdgcn_rcpf(base + (float)g);
                tc[g] = 2.0f * __builtin_amdgcn_cosf(inv);
                c[g]  = __builtin_amdgcn_cosf(__builtin_amdgcn_fractf(sf  * inv));
                cp[g] = __builtin_amdgcn_cosf(__builtin_amdgcn_fractf(sm1 * inv));
            }
            #pragma unroll
            for (int sp = 0; sp < 8; ++sp) {
                float w = 0.f;
                #pragma unroll
                for (int g = 0; g < 8; ++g) w = fmaf(pv[g], c[g], w);
                sm.W[sp][ip][j] = f2bf(w);
                #pragma unroll
                for (int g = 0; g < 8; ++g) {
                    float cn = fmaf(tc[g], c[g], -cp[g]);
                    cp[g] = c[g]; c[g] = cn;
                }
            }
        }
    }
    __syncthreads();

    // ---- phase B: thread (s2 = t/48, ip-pair, b); 2 i' x 96 j ----
    {
        const int s2  = t / 48;
        const int rem = t % 48;
        const int ipq = rem / 8;          // [0,6)
        const int bb  = rem % 8;
        const int ia  = ipq * 2, ib = ia + 1;
        float accA = 0.f, accB = 0.f;
        const uint16_t* w0 = &sm.W[s2][ia][0];
        const uint16_t* w1 = &sm.W[s2][ib][0];
        const float*    zz = &sm.zs[s2][bb][0];
        #pragma unroll 3
        for (int j0 = 0; j0 < 96; j0 += 8) {
            short8 wa = *(const short8*)(w0 + j0);
            short8 wb = *(const short8*)(w1 + j0);
            float4 z0 = *(const float4*)(zz + j0);
            float4 z1 = *(const float4*)(zz + j0 + 4);
            accA = fmaf(bf2f((uint16_t)wa[0]), z0.x, accA);
            accB = fmaf(bf2f((uint16_t)wb[0]), z0.x, accB);
            accA = fmaf(bf2f((uint16_t)wa[1]), z0.y, accA);
            accB = fmaf(bf2f((uint16_t)wb[1]), z0.y, accB);
            accA = fmaf(bf2f((uint16_t)wa[2]), z0.z, accA);
            accB = fmaf(bf2f((uint16_t)wb[2]), z0.z, accB);
            accA = fmaf(bf2f((uint16_t)wa[3]), z0.w, accA);
            accB = fmaf(bf2f((uint16_t)wb[3]), z0.w, accB);
            accA = fmaf(bf2f((uint16_t)wa[4]), z1.x, accA);
            accB = fmaf(bf2f((uint16_t)wb[4]), z1.x, accB);
            accA = fmaf(bf2f((uint16_t)wa[5]), z1.y, accA);
            accB = fmaf(bf2f((uint16_t)wb[5]), z1.y, accB);
            accA = fmaf(bf2f((uint16_t)wa[6]), z1.z, accA);
            accB = fmaf(bf2f((uint16_t)wb[6]), z1.z, accB);
            accA = fmaf(bf2f((uint16_t)wa[7]), z1.w, accA);
            accB = fmaf(bf2f((uint16_t)wb[7]), z1.w, accB);
        }
        // residual (contiguous f32x2) + stage
        float2 r2 = *(const float2*)(Z0 + (size_t)(s0 + s2) * 768 + bb * 96 + i0 + ia);
        sm.stage[ia][bb][s2] = f2bf(accA + r2.x);
        sm.stage[ib][bb][s2] = f2bf(accB + r2.y);
    }
    __syncthreads();

    // ---- Vt write (sg-tiled): 16 B per (b,i) row into block-private region --
    if (t < 96) {
        int ip = t >> 3, bb = t & 7;
        uint4 v = *(const uint4*)&sm.stage[ip][bb][0];
        *(uint4*)(Vt + ((size_t)sg * 768 + (size_t)bb * 96 + i0 + ip) * 8) = v;
    }
}

// ---------------------------------------------------------------------------
// K3: out[b,t,i] = sum_s Lt[t][s]*Vt_tiled[s/8][b*96+i][s%8]
// Split-K x4 + i-half z-split: grid (64,8,2), 256 thr, LDS combine.
// Vt addressing for the sg-tiled layout; same elements, same order.
// ---------------------------------------------------------------------------
__global__ __launch_bounds__(256, 4) void k3_mfma(
    const uint16_t* __restrict__ Lt, const uint16_t* __restrict__ Vt,
    float* __restrict__ out)
{
    __shared__ float racc[3][64][13];
    const int lane = threadIdx.x & 63;
    const int kw   = threadIdx.x >> 6;      // 0..3
    const int m    = lane & 15;
    const int quad = lane >> 4;
    const int t0   = blockIdx.x * 16;
    const int b    = blockIdx.y;
    const int ih   = blockIdx.z;            // i-half

    const uint16_t* Lp = Lt + (size_t)(t0 + m) * 1024 + kw * 256 + quad * 8;
    // s-index for chunk kc: kw*256 + quad*8 + kc*32 -> tile = kw*32+quad+kc*4
    const uint16_t* Vp = Vt + ((size_t)(kw * 32 + quad) * 768 +
                               (size_t)b * 96 + ih * 48 + m) * 8;

    f32x4 acc[3];
    #pragma unroll
    for (int ii = 0; ii < 3; ++ii) acc[ii] = (f32x4){0.f, 0.f, 0.f, 0.f};

    short8 a = *(const short8*)Lp;
    short8 bv[3];
    #pragma unroll
    for (int ii = 0; ii < 3; ++ii)
        bv[ii] = *(const short8*)(Vp + ii * 128);           // +ii*16 rows

    for (int kc = 0; kc < 7; ++kc) {
        short8 an = *(const short8*)(Lp + (kc + 1) * 32);
        short8 bn[3];
        #pragma unroll
        for (int ii = 0; ii < 3; ++ii)
            bn[ii] = *(const short8*)(Vp + (size_t)(kc + 1) * 24576 + ii * 128);
        #pragma unroll
        for (int ii = 0; ii < 3; ++ii)
            acc[ii] = __builtin_amdgcn_mfma_f32_16x16x32_bf16(a, bv[ii], acc[ii], 0, 0, 0);
        a = an;
        #pragma unroll
        for (int ii = 0; ii < 3; ++ii) bv[ii] = bn[ii];
    }
    #pragma unroll
    for (int ii = 0; ii < 3; ++ii)
        acc[ii] = __builtin_amdgcn_mfma_f32_16x16x32_bf16(a, bv[ii], acc[ii], 0, 0, 0);

    if (kw > 0) {
        #pragma unroll
        for (int ii = 0; ii < 3; ++ii)
            #pragma unroll
            for (int r = 0; r < 4; ++r)
                racc[kw - 1][lane][ii * 4 + r] = acc[ii][r];
    }
    __syncthreads();
    if (kw == 0) {
        float* po = out + (size_t)b * BSTRIDE;
        #pragma unroll
        for (int ii = 0; ii < 3; ++ii)
            #pragma unroll
            for (int r = 0; r < 4; ++r)
                po[(size_t)(t0 + quad * 4 + r) * 96 + ih * 48 + ii * 16 + m] =
                    acc[ii][r] + racc[0][lane][ii * 4 + r] +
                    racc[1][lane][ii * 4 + r] + racc[2][lane][ii * 4 + r];
    }
}

extern "C" void kernel_launch(void* const* d_in, const int* in_sizes, int n_in,
                              void* d_out, int out_size, void* d_ws, size_t ws_size,
                              hipStream_t stream)
{
    const float* x     = (const float*)d_in[0];
    const float* M     = (const float*)d_in[1];
    const float* P     = (const float*)d_in[2];
    const float* Lnk   = (const float*)d_in[3];
    const float* gamma = (const float*)d_in[4];
    const float* beta  = (const float*)d_in[5];
    float* out = (float*)d_out;

    uint8_t* ws = (uint8_t*)d_ws;
    uint16_t* Lt = (uint16_t*)ws;                 // 2,097,152 B
    uint16_t* Vt = (uint16_t*)(ws + 2097152);     // 1,572,864 B (tiled [128][768][8])
    float*    Z0 = (float*)(ws + 3670016);        // 3,145,728 B
    float*    Z  = (float*)(ws + 6815744);        // 3,145,728 B

    kA<<<768, 384, 0, stream>>>(x, M, Lnk, gamma, beta, Z0, Z, Lt);
    kB<<<1024, 384, 0, stream>>>(P, Z, Z0, Vt);
    k3_mfma<<<dim3(64, 8, 2), 256, 0, stream>>>(Lt, Vt, out);
}

// Round 13
// 105.761 us; speedup vs baseline: 1.2235x; 1.0062x over previous
//
#include <hip/hip_runtime.h>
#include <hip/hip_cooperative_groups.h>
#include <cstdint>
#include <cstddef>

namespace cg = cooperative_groups;

#define BSTRIDE 98304   // 1024*96 floats per batch

typedef __attribute__((ext_vector_type(8))) short short8;
typedef __attribute__((ext_vector_type(4))) float f32x4;

__device__ __forceinline__ uint16_t f2bf(float x) {
    uint32_t u = __float_as_uint(x);
    return (uint16_t)((u + 0x7FFF + ((u >> 16) & 1)) >> 16);   // RNE
}
__device__ __forceinline__ float bf2f(uint16_t b) {
    return __uint_as_float(((uint32_t)b) << 16);
}

// ---- shared-memory layouts (r12-proven) ----
struct SmemA_ {
    union {
        float M[96][97];                         // 37248 B
        struct { float zb[16][97]; float ps1[16][8];
                 float ps2[16][8]; float stats[16][2]; } ln;
    } m;
    float xs[16][96];                            // 6144 B
};
struct SmemB_ {
    float    zs[8][8][100];    // 25600 B
    uint16_t W[8][12][104];    // 19968 B
    uint16_t stage[12][8][8];  // 1536 B
};
union SmemU {
    SmemA_ a;                  // 43392 B
    SmemB_ b;                  // 47104 B  (max)
    float  racc[3][64][13];    // 9984 B
    float  T[64][65];          // 16640 B
};

// ===========================================================================
// mega: all three phases, one cooperative launch.  768 blocks x 384 thr,
// 47.1 KB LDS -> exactly 3 blocks/CU co-resident.
// ===========================================================================
__global__ __launch_bounds__(384, 5) void mega(
    const float* __restrict__ x, const float* __restrict__ M,
    const float* __restrict__ P, const float* __restrict__ L,
    const float* __restrict__ gamma, const float* __restrict__ beta,
    float* __restrict__ Z0, float* __restrict__ Z,
    uint16_t* __restrict__ Lt, uint16_t* __restrict__ Vt,
    float* __restrict__ out)
{
    __shared__ SmemU sm;
    const int t  = threadIdx.x;
    const int bx = blockIdx.x;
    cg::grid_group grid = cg::this_grid();

    // ===================== phase 1: proj+LN / Lt transpose =====================
    if (bx >= 512) {
        const int bx2 = bx - 512;
        const int s0 = (bx2 & 15) * 64, t0 = (bx2 >> 4) * 64;
        if (t < 64) {
            for (int r = 0; r < 64; ++r)
                sm.T[r][t] = L[(size_t)(s0 + r) * 1024 + t0 + t];
        }
        __syncthreads();
        if (t < 64) {
            uint16_t* orow = Lt + (size_t)(t0 + t) * 1024 + s0;
            #pragma unroll
            for (int c4 = 0; c4 < 16; ++c4) {
                uint32_t u01 = (uint32_t)f2bf(sm.T[c4*4+0][t]) |
                               ((uint32_t)f2bf(sm.T[c4*4+1][t]) << 16);
                uint32_t u23 = (uint32_t)f2bf(sm.T[c4*4+2][t]) |
                               ((uint32_t)f2bf(sm.T[c4*4+3][t]) << 16);
                uint2 o; o.x = u01; o.y = u23;
                *(uint2*)(orow + c4 * 4) = o;
            }
        }
    } else {
        const int R0 = bx * 16;
        const int b  = R0 >> 10;
        const int sb = R0 & 1023;

        #pragma unroll
        for (int k = 0; k < 6; ++k) {
            int mm = t + 384 * k;
            int i = mm / 24, j0 = (mm % 24) * 4;
            float4 v = *(const float4*)(M + (size_t)i * 96 + j0);
            sm.a.m.M[i][j0]   = v.x; sm.a.m.M[i][j0+1] = v.y;
            sm.a.m.M[i][j0+2] = v.z; sm.a.m.M[i][j0+3] = v.w;
        }
        {
            int row = t / 24, j0 = (t % 24) * 4;
            float4 v = *(const float4*)(x + (size_t)(R0 + row) * 96 + j0);
            *(float4*)&sm.a.xs[row][j0] = v;
        }
        __syncthreads();

        const int e = t % 96;
        const int q = t / 96;
        float acc[4] = {0.f, 0.f, 0.f, 0.f};
        for (int j0 = 0; j0 < 96; j0 += 4) {
            float m0 = sm.a.m.M[e][j0+0], m1 = sm.a.m.M[e][j0+1];
            float m2 = sm.a.m.M[e][j0+2], m3 = sm.a.m.M[e][j0+3];
            #pragma unroll
            for (int rr = 0; rr < 4; ++rr) {
                float4 xv = *(const float4*)&sm.a.xs[q * 4 + rr][j0];
                acc[rr] = fmaf(m0, xv.x, fmaf(m1, xv.y,
                          fmaf(m2, xv.z, fmaf(m3, xv.w, acc[rr]))));
            }
        }
        __syncthreads();
        #pragma unroll
        for (int rr = 0; rr < 4; ++rr) sm.a.m.ln.zb[q * 4 + rr][e] = acc[rr];
        __syncthreads();

        if (t < 128) {
            int r = t >> 3, seg = t & 7;
            float s1 = 0.f, s2 = 0.f;
            #pragma unroll
            for (int k = 0; k < 12; ++k) {
                float v = sm.a.m.ln.zb[r][seg * 12 + k];
                s1 += v; s2 += v * v;
            }
            sm.a.m.ln.ps1[r][seg] = s1; sm.a.m.ln.ps2[r][seg] = s2;
        }
        __syncthreads();
        if (t < 16) {
            float s1 = 0.f, s2 = 0.f;
            #pragma unroll
            for (int k = 0; k < 8; ++k) { s1 += sm.a.m.ln.ps1[t][k]; s2 += sm.a.m.ln.ps2[t][k]; }
            float mu  = s1 * (1.f / 96.f);
            float var = s2 * (1.f / 96.f) - mu * mu;
            sm.a.m.ln.stats[t][0] = mu;
            sm.a.m.ln.stats[t][1] = rsqrtf(var + 1e-5f);
        }
        __syncthreads();
        {
            float gm = gamma[e], bt = beta[e];
            #pragma unroll
            for (int rr = 0; rr < 4; ++rr) {
                int r = q * 4 + rr;
                float z  = acc[rr];
                float mu = sm.a.m.ln.stats[r][0], rs = sm.a.m.ln.stats[r][1];
                size_t o = (size_t)(sb + r) * 768 + (size_t)b * 96 + e;
                Z0[o] = z;
                Z[o]  = (z - mu) * rs * gm + bt;
            }
        }
    }

    __threadfence();
    grid.sync();

    // ===================== phase 2: kB units (1024 over 768 blocks) ==========
    for (int u = bx; u < 1024; u += 768) {
        const int sg = u & 127;
        const int ih = u >> 7;
        const int s0 = sg * 8;
        const int i0 = ih * 12;

        #pragma unroll
        for (int k = 0; k < 4; ++k) {
            int c = t + 384 * k;
            int elem = c * 4;
            int sp = elem / 768, rem = elem - sp * 768;
            int bb = rem / 96,  j0 = rem - bb * 96;
            float4 v = *(const float4*)(Z + (size_t)s0 * 768 + elem);
            *(float4*)&sm.b.zs[sp][bb][j0] = v;
        }

        {
            const int j   = t % 96;
            const int iqb = t / 96;
            const float sf  = (float)s0;
            const float sm1 = sf - 1.0f;
            #pragma unroll 1
            for (int kk = 0; kk < 3; ++kk) {
                const int ip = kk * 4 + iqb;
                const int ig = i0 + ip;
                const float* Pp = P + ((size_t)ig * 96 + j) * 8;
                float4 pa = *(const float4*)(Pp);
                float4 pb = *(const float4*)(Pp + 4);
                float pv[8] = {pa.x, pa.y, pa.z, pa.w, pb.x, pb.y, pb.z, pb.w};
                float base = (float)((ig * 96 + j) * 8 + 2);
                float c[8], cp[8], tc[8];
                #pragma unroll
                for (int g = 0; g < 8; ++g) {
                    float inv = __builtin_amdgcn_rcpf(base + (float)g);
                    tc[g] = 2.0f * __builtin_amdgcn_cosf(inv);
                    c[g]  = __builtin_amdgcn_cosf(__builtin_amdgcn_fractf(sf  * inv));
                    cp[g] = __builtin_amdgcn_cosf(__builtin_amdgcn_fractf(sm1 * inv));
                }
                #pragma unroll
                for (int sp = 0; sp < 8; ++sp) {
                    float w = 0.f;
                    #pragma unroll
                    for (int g = 0; g < 8; ++g) w = fmaf(pv[g], c[g], w);
                    sm.b.W[sp][ip][j] = f2bf(w);
                    #pragma unroll
                    for (int g = 0; g < 8; ++g) {
                        float cn = fmaf(tc[g], c[g], -cp[g]);
                        cp[g] = c[g]; c[g] = cn;
                    }
                }
            }
        }
        __syncthreads();

        {
            const int s2  = t / 48;
            const int rem = t % 48;
            const int ipq = rem / 8;
            const int bb  = rem % 8;
            const int ia  = ipq * 2, ib = ia + 1;
            float accA = 0.f, accB = 0.f;
            const uint16_t* w0 = &sm.b.W[s2][ia][0];
            const uint16_t* w1 = &sm.b.W[s2][ib][0];
            const float*    zz = &sm.b.zs[s2][bb][0];
            #pragma unroll 3
            for (int j0 = 0; j0 < 96; j0 += 8) {
                short8 wa = *(const short8*)(w0 + j0);
                short8 wb = *(const short8*)(w1 + j0);
                float4 z0 = *(const float4*)(zz + j0);
                float4 z1 = *(const float4*)(zz + j0 + 4);
                accA = fmaf(bf2f((uint16_t)wa[0]), z0.x, accA);
                accB = fmaf(bf2f((uint16_t)wb[0]), z0.x, accB);
                accA = fmaf(bf2f((uint16_t)wa[1]), z0.y, accA);
                accB = fmaf(bf2f((uint16_t)wb[1]), z0.y, accB);
                accA = fmaf(bf2f((uint16_t)wa[2]), z0.z, accA);
                accB = fmaf(bf2f((uint16_t)wb[2]), z0.z, accB);
                accA = fmaf(bf2f((uint16_t)wa[3]), z0.w, accA);
                accB = fmaf(bf2f((uint16_t)wb[3]), z0.w, accB);
                accA = fmaf(bf2f((uint16_t)wa[4]), z1.x, accA);
                accB = fmaf(bf2f((uint16_t)wb[4]), z1.x, accB);
                accA = fmaf(bf2f((uint16_t)wa[5]), z1.y, accA);
                accB = fmaf(bf2f((uint16_t)wb[5]), z1.y, accB);
                accA = fmaf(bf2f((uint16_t)wa[6]), z1.z, accA);
                accB = fmaf(bf2f((uint16_t)wb[6]), z1.z, accB);
                accA = fmaf(bf2f((uint16_t)wa[7]), z1.w, accA);
                accB = fmaf(bf2f((uint16_t)wb[7]), z1.w, accB);
            }
            float2 r2 = *(const float2*)(Z0 + (size_t)(s0 + s2) * 768 + bb * 96 + i0 + ia);
            sm.b.stage[ia][bb][s2] = f2bf(accA + r2.x);
            sm.b.stage[ib][bb][s2] = f2bf(accB + r2.y);
        }
        __syncthreads();

        if (t < 96) {
            int ip = t >> 3, bb = t & 7;
            uint4 v = *(const uint4*)&sm.b.stage[ip][bb][0];
            *(uint4*)(Vt + ((size_t)sg * 768 + (size_t)bb * 96 + i0 + ip) * 8) = v;
        }
    }

    __threadfence();
    grid.sync();

    // ===================== phase 3: k3 units (1024 over 768 blocks) ==========
    for (int u = bx; u < 1024; u += 768) {
        const int tq  = u & 63;
        const int b   = (u >> 6) & 7;
        const int ih2 = u >> 9;
        const bool act = (t < 256);
        const int lane = t & 63;
        const int kw   = (t >> 6) & 3;
        const int m    = lane & 15;
        const int quad = lane >> 4;
        const int t0   = tq * 16;

        f32x4 acc3[3];
        #pragma unroll
        for (int ii = 0; ii < 3; ++ii) acc3[ii] = (f32x4){0.f, 0.f, 0.f, 0.f};

        if (act) {
            const uint16_t* Lp = Lt + (size_t)(t0 + m) * 1024 + kw * 256 + quad * 8;
            const uint16_t* Vp = Vt + ((size_t)(kw * 32 + quad) * 768 +
                                       (size_t)b * 96 + ih2 * 48 + m) * 8;
            short8 a = *(const short8*)Lp;
            short8 bv[3];
            #pragma unroll
            for (int ii = 0; ii < 3; ++ii)
                bv[ii] = *(const short8*)(Vp + ii * 128);

            for (int kc = 0; kc < 7; ++kc) {
                short8 an = *(const short8*)(Lp + (kc + 1) * 32);
                short8 bn[3];
                #pragma unroll
                for (int ii = 0; ii < 3; ++ii)
                    bn[ii] = *(const short8*)(Vp + (size_t)(kc + 1) * 24576 + ii * 128);
                #pragma unroll
                for (int ii = 0; ii < 3; ++ii)
                    acc3[ii] = __builtin_amdgcn_mfma_f32_16x16x32_bf16(a, bv[ii], acc3[ii], 0, 0, 0);
                a = an;
                #pragma unroll
                for (int ii = 0; ii < 3; ++ii) bv[ii] = bn[ii];
            }
            #pragma unroll
            for (int ii = 0; ii < 3; ++ii)
                acc3[ii] = __builtin_amdgcn_mfma_f32_16x16x32_bf16(a, bv[ii], acc3[ii], 0, 0, 0);

            if (kw > 0) {
                #pragma unroll
                for (int ii = 0; ii < 3; ++ii)
                    #pragma unroll
                    for (int r = 0; r < 4; ++r)
                        sm.racc[kw - 1][lane][ii * 4 + r] = acc3[ii][r];
            }
        }
        __syncthreads();
        if (act && kw == 0) {
            float* po = out + (size_t)b * BSTRIDE;
            #pragma unroll
            for (int ii = 0; ii < 3; ++ii)
                #pragma unroll
                for (int r = 0; r < 4; ++r)
                    po[(size_t)(t0 + quad * 4 + r) * 96 + ih2 * 48 + ii * 16 + m] =
                        acc3[ii][r] + sm.racc[0][lane][ii * 4 + r] +
                        sm.racc[1][lane][ii * 4 + r] + sm.racc[2][lane][ii * 4 + r];
        }
        __syncthreads();   // close racc reuse across loop iterations
    }
}

// ===========================================================================
// Fallback path: r12-proven three kernels (verbatim)
// ===========================================================================
union SmemA {
    SmemA_ a;
    struct { float T[64][65]; } kl;
};

__global__ __launch_bounds__(384, 4) void kA(
    const float* __restrict__ x, const float* __restrict__ M,
    const float* __restrict__ L,
    const float* __restrict__ gamma, const float* __restrict__ beta,
    float* __restrict__ Z0, float* __restrict__ Z, uint16_t* __restrict__ Lt)
{
    __shared__ SmemA sm;
    const int t  = threadIdx.x;
    const int bx = blockIdx.x;

    if (bx >= 512) {
        const int bx2 = bx - 512;
        const int s0 = (bx2 & 15) * 64, t0 = (bx2 >> 4) * 64;
        if (t < 64) {
            for (int r = 0; r < 64; ++r)
                sm.kl.T[r][t] = L[(size_t)(s0 + r) * 1024 + t0 + t];
        }
        __syncthreads();
        if (t < 64) {
            uint16_t* orow = Lt + (size_t)(t0 + t) * 1024 + s0;
            #pragma unroll
            for (int c4 = 0; c4 < 16; ++c4) {
                uint32_t u01 = (uint32_t)f2bf(sm.kl.T[c4*4+0][t]) |
                               ((uint32_t)f2bf(sm.kl.T[c4*4+1][t]) << 16);
                uint32_t u23 = (uint32_t)f2bf(sm.kl.T[c4*4+2][t]) |
                               ((uint32_t)f2bf(sm.kl.T[c4*4+3][t]) << 16);
                uint2 o; o.x = u01; o.y = u23;
                *(uint2*)(orow + c4 * 4) = o;
            }
        }
        return;
    }

    const int R0 = bx * 16;
    const int b  = R0 >> 10;
    const int sb = R0 & 1023;

    #pragma unroll
    for (int k = 0; k < 6; ++k) {
        int mm = t + 384 * k;
        int i = mm / 24, j0 = (mm % 24) * 4;
        float4 v = *(const float4*)(M + (size_t)i * 96 + j0);
        sm.a.m.M[i][j0]   = v.x; sm.a.m.M[i][j0+1] = v.y;
        sm.a.m.M[i][j0+2] = v.z; sm.a.m.M[i][j0+3] = v.w;
    }
    {
        int row = t / 24, j0 = (t % 24) * 4;
        float4 v = *(const float4*)(x + (size_t)(R0 + row) * 96 + j0);
        *(float4*)&sm.a.xs[row][j0] = v;
    }
    __syncthreads();

    const int e = t % 96;
    const int q = t / 96;
    float acc[4] = {0.f, 0.f, 0.f, 0.f};
    for (int j0 = 0; j0 < 96; j0 += 4) {
        float m0 = sm.a.m.M[e][j0+0], m1 = sm.a.m.M[e][j0+1];
        float m2 = sm.a.m.M[e][j0+2], m3 = sm.a.m.M[e][j0+3];
        #pragma unroll
        for (int rr = 0; rr < 4; ++rr) {
            float4 xv = *(const float4*)&sm.a.xs[q * 4 + rr][j0];
            acc[rr] = fmaf(m0, xv.x, fmaf(m1, xv.y,
                      fmaf(m2, xv.z, fmaf(m3, xv.w, acc[rr]))));
        }
    }
    __syncthreads();
    #pragma unroll
    for (int rr = 0; rr < 4; ++rr) sm.a.m.ln.zb[q * 4 + rr][e] = acc[rr];
    __syncthreads();

    if (t < 128) {
        int r = t >> 3, seg = t & 7;
        float s1 = 0.f, s2 = 0.f;
        #pragma unroll
        for (int k = 0; k < 12; ++k) {
            float v = sm.a.m.ln.zb[r][seg * 12 + k];
            s1 += v; s2 += v * v;
        }
        sm.a.m.ln.ps1[r][seg] = s1; sm.a.m.ln.ps2[r][seg] = s2;
    }
    __syncthreads();
    if (t < 16) {
        float s1 = 0.f, s2 = 0.f;
        #pragma unroll
        for (int k = 0; k < 8; ++k) { s1 += sm.a.m.ln.ps1[t][k]; s2 += sm.a.m.ln.ps2[t][k]; }
        float mu  = s1 * (1.f / 96.f);
        float var = s2 * (1.f / 96.f) - mu * mu;
        sm.a.m.ln.stats[t][0] = mu;
        sm.a.m.ln.stats[t][1] = rsqrtf(var + 1e-5f);
    }
    __syncthreads();

    {
        float gm = gamma[e], bt = beta[e];
        #pragma unroll
        for (int rr = 0; rr < 4; ++rr) {
            int r = q * 4 + rr;
            float z  = acc[rr];
            float mu = sm.a.m.ln.stats[r][0], rs = sm.a.m.ln.stats[r][1];
            size_t o = (size_t)(sb + r) * 768 + (size_t)b * 96 + e;
            Z0[o] = z;
            Z[o]  = (z - mu) * rs * gm + bt;
        }
    }
}

__global__ __launch_bounds__(384, 4) void kB(
    const float* __restrict__ P, const float* __restrict__ Z,
    const float* __restrict__ Z0, uint16_t* __restrict__ Vt)
{
    __shared__ SmemB_ sm;
    const int t  = threadIdx.x;
    const int sg = blockIdx.x & 127;
    const int ih = blockIdx.x >> 7;
    const int s0 = sg * 8;
    const int i0 = ih * 12;

    #pragma unroll
    for (int k = 0; k < 4; ++k) {
        int c = t + 384 * k;
        int elem = c * 4;
        int sp = elem / 768, rem = elem - sp * 768;
        int bb = rem / 96,  j0 = rem - bb * 96;
        float4 v = *(const float4*)(Z + (size_t)s0 * 768 + elem);
        *(float4*)&sm.zs[sp][bb][j0] = v;
    }

    {
        const int j   = t % 96;
        const int iqb = t / 96;
        const float sf  = (float)s0;
        const float sm1 = sf - 1.0f;
        #pragma unroll 1
        for (int kk = 0; kk < 3; ++kk) {
            const int ip = kk * 4 + iqb;
            const int ig = i0 + ip;
            const float* Pp = P + ((size_t)ig * 96 + j) * 8;
            float4 pa = *(const float4*)(Pp);
            float4 pb = *(const float4*)(Pp + 4);
            float pv[8] = {pa.x, pa.y, pa.z, pa.w, pb.x, pb.y, pb.z, pb.w};
            float base = (float)((ig * 96 + j) * 8 + 2);
            float c[8], cp[8], tc[8];
            #pragma unroll
            for (int g = 0; g < 8; ++g) {
                float inv = __builtin_amdgcn_rcpf(base + (float)g);
                tc[g] = 2.0f * __builtin_amdgcn_cosf(inv);
                c[g]  = __builtin_amdgcn_cosf(__builtin_amdgcn_fractf(sf  * inv));
                cp[g] = __builtin_amdgcn_cosf(__builtin_amdgcn_fractf(sm1 * inv));
            }
            #pragma unroll
            for (int sp = 0; sp < 8; ++sp) {
                float w = 0.f;
                #pragma unroll
                for (int g = 0; g < 8; ++g) w = fmaf(pv[g], c[g], w);
                sm.W[sp][ip][j] = f2bf(w);
                #pragma unroll
                for (int g = 0; g < 8; ++g) {
                    float cn = fmaf(tc[g], c[g], -cp[g]);
                    cp[g] = c[g]; c[g] = cn;
                }
            }
        }
    }
    __syncthreads();

    {
        const int s2  = t / 48;
        const int rem = t % 48;
        const int ipq = rem / 8;
        const int bb  = rem % 8;
        const int ia  = ipq * 2, ib = ia + 1;
        float accA = 0.f, accB = 0.f;
        const uint16_t* w0 = &sm.W[s2][ia][0];
        const uint16_t* w1 = &sm.W[s2][ib][0];
        const float*    zz = &sm.zs[s2][bb][0];
        #pragma unroll 3
        for (int j0 = 0; j0 < 96; j0 += 8) {
            short8 wa = *(const short8*)(w0 + j0);
            short8 wb = *(const short8*)(w1 + j0);
            float4 z0 = *(const float4*)(zz + j0);
            float4 z1 = *(const float4*)(zz + j0 + 4);
            accA = fmaf(bf2f((uint16_t)wa[0]), z0.x, accA);
            accB = fmaf(bf2f((uint16_t)wb[0]), z0.x, accB);
            accA = fmaf(bf2f((uint16_t)wa[1]), z0.y, accA);
            accB = fmaf(bf2f((uint16_t)wb[1]), z0.y, accB);
            accA = fmaf(bf2f((uint16_t)wa[2]), z0.z, accA);
            accB = fmaf(bf2f((uint16_t)wb[2]), z0.z, accB);
            accA = fmaf(bf2f((uint16_t)wa[3]), z0.w, accA);
            accB = fmaf(bf2f((uint16_t)wb[3]), z0.w, accB);
            accA = fmaf(bf2f((uint16_t)wa[4]), z1.x, accA);
            accB = fmaf(bf2f((uint16_t)wb[4]), z1.x, accB);
            accA = fmaf(bf2f((uint16_t)wa[5]), z1.y, accA);
            accB = fmaf(bf2f((uint16_t)wb[5]), z1.y, accB);
            accA = fmaf(bf2f((uint16_t)wa[6]), z1.z, accA);
            accB = fmaf(bf2f((uint16_t)wb[6]), z1.z, accB);
            accA = fmaf(bf2f((uint16_t)wa[7]), z1.w, accA);
            accB = fmaf(bf2f((uint16_t)wb[7]), z1.w, accB);
        }
        float2 r2 = *(const float2*)(Z0 + (size_t)(s0 + s2) * 768 + bb * 96 + i0 + ia);
        sm.stage[ia][bb][s2] = f2bf(accA + r2.x);
        sm.stage[ib][bb][s2] = f2bf(accB + r2.y);
    }
    __syncthreads();

    if (t < 96) {
        int ip = t >> 3, bb = t & 7;
        uint4 v = *(const uint4*)&sm.stage[ip][bb][0];
        *(uint4*)(Vt + ((size_t)sg * 768 + (size_t)bb * 96 + i0 + ip) * 8) = v;
    }
}

__global__ __launch_bounds__(256, 4) void k3_mfma(
    const uint16_t* __restrict__ Lt, const uint16_t* __restrict__ Vt,
    float* __restrict__ out)
{
    __shared__ float racc[3][64][13];
    const int lane = threadIdx.x & 63;
    const int kw   = threadIdx.x >> 6;
    const int m    = lane & 15;
    const int quad = lane >> 4;
    const int t0   = blockIdx.x * 16;
    const int b    = blockIdx.y;
    const int ih   = blockIdx.z;

    const uint16_t* Lp = Lt + (size_t)(t0 + m) * 1024 + kw * 256 + quad * 8;
    const uint16_t* Vp = Vt + ((size_t)(kw * 32 + quad) * 768 +
                               (size_t)b * 96 + ih * 48 + m) * 8;

    f32x4 acc[3];
    #pragma unroll
    for (int ii = 0; ii < 3; ++ii) acc[ii] = (f32x4){0.f, 0.f, 0.f, 0.f};

    short8 a = *(const short8*)Lp;
    short8 bv[3];
    #pragma unroll
    for (int ii = 0; ii < 3; ++ii)
        bv[ii] = *(const short8*)(Vp + ii * 128);

    for (int kc = 0; kc < 7; ++kc) {
        short8 an = *(const short8*)(Lp + (kc + 1) * 32);
        short8 bn[3];
        #pragma unroll
        for (int ii = 0; ii < 3; ++ii)
            bn[ii] = *(const short8*)(Vp + (size_t)(kc + 1) * 24576 + ii * 128);
        #pragma unroll
        for (int ii = 0; ii < 3; ++ii)
            acc[ii] = __builtin_amdgcn_mfma_f32_16x16x32_bf16(a, bv[ii], acc[ii], 0, 0, 0);
        a = an;
        #pragma unroll
        for (int ii = 0; ii < 3; ++ii) bv[ii] = bn[ii];
    }
    #pragma unroll
    for (int ii = 0; ii < 3; ++ii)
        acc[ii] = __builtin_amdgcn_mfma_f32_16x16x32_bf16(a, bv[ii], acc[ii], 0, 0, 0);

    if (kw > 0) {
        #pragma unroll
        for (int ii = 0; ii < 3; ++ii)
            #pragma unroll
            for (int r = 0; r < 4; ++r)
                racc[kw - 1][lane][ii * 4 + r] = acc[ii][r];
    }
    __syncthreads();
    if (kw == 0) {
        float* po = out + (size_t)b * BSTRIDE;
        #pragma unroll
        for (int ii = 0; ii < 3; ++ii)
            #pragma unroll
            for (int r = 0; r < 4; ++r)
                po[(size_t)(t0 + quad * 4 + r) * 96 + ih * 48 + ii * 16 + m] =
                    acc[ii][r] + racc[0][lane][ii * 4 + r] +
                    racc[1][lane][ii * 4 + r] + racc[2][lane][ii * 4 + r];
    }
}

extern "C" void kernel_launch(void* const* d_in, const int* in_sizes, int n_in,
                              void* d_out, int out_size, void* d_ws, size_t ws_size,
                              hipStream_t stream)
{
    const float* x     = (const float*)d_in[0];
    const float* M     = (const float*)d_in[1];
    const float* P     = (const float*)d_in[2];
    const float* Lnk   = (const float*)d_in[3];
    const float* gamma = (const float*)d_in[4];
    const float* beta  = (const float*)d_in[5];
    float* out = (float*)d_out;

    uint8_t* ws = (uint8_t*)d_ws;
    uint16_t* Lt = (uint16_t*)ws;                 // 2,097,152 B
    uint16_t* Vt = (uint16_t*)(ws + 2097152);     // 1,572,864 B (tiled [128][768][8])
    float*    Z0 = (float*)(ws + 3670016);        // 3,145,728 B
    float*    Z  = (float*)(ws + 6815744);        // 3,145,728 B

    // one-time host-side occupancy check for the cooperative path
    static int coop_state = -1;                   // -1 unknown, 0 no, 1 yes
    if (coop_state == -1) {
        int nb = 0;
        hipError_t e = hipOccupancyMaxActiveBlocksPerMultiprocessor(
            &nb, reinterpret_cast<const void*>(mega), 384, 0);
        coop_state = (e == hipSuccess && nb >= 3) ? 1 : 0;
    }

    bool launched = false;
    if (coop_state == 1) {
        void* args[] = {
            (void*)&x, (void*)&M, (void*)&P, (void*)&Lnk,
            (void*)&gamma, (void*)&beta,
            (void*)&Z0, (void*)&Z, (void*)&Lt, (void*)&Vt, (void*)&out
        };
        hipError_t e = hipLaunchCooperativeKernel(
            reinterpret_cast<const void*>(mega), dim3(768), dim3(384),
            args, 0, stream);
        if (e == hipSuccess) launched = true;
        else coop_state = 0;                      // don't retry
    }
    if (!launched) {
        kA<<<768, 384, 0, stream>>>(x, M, Lnk, gamma, beta, Z0, Z, Lt);
        kB<<<1024, 384, 0, stream>>>(P, Z, Z0, Vt);
        k3_mfma<<<dim3(64, 8, 2), 256, 0, stream>>>(Lt, Vt, out);
    }
}